// Round 12
// baseline (488.386 us; speedup 1.0000x reference)
//
#include <hip/hip_runtime.h>

// ChainMessagePassing: out[n] = sum over edges with dst==n of x[src], over two edge lists.
// x: [N=100000, 64] fp32; indices: [2, E=3200000] (src row 0, dst row 1), int64 or int32.
//
// R15: gather DS-pipe fix on top of R14 (416us: gather 205.6 @ FETCH 194MB = near-
// compulsory traffic; prep ~210 via two-pass radix). Accounting showed gather is
// DS-issue-bound (~1 broadcast ds_read_b32/edge + 2 bound-reads/4.9-edge bin on the
// shared per-CU LDS pipe; VALU 17%, HBM 1.1TB/s both far from limits). Changes:
//  (a) pair-aligned bin starts (padded count c+(c&1)) -> sorted walked via uint2
//      (ds_read_b64, 2 indices/DS-instr); odd tails read a never-used gap slot,
//      predicated by group-uniform (e+1<re). 8-deep main loop for long runs.
//  (b) packed bounds: post-scatter phase binoff[i] |= cnt[i]<<16 (both <2^14) ->
//      1 b32 per bin instead of 2.
//  LDS 26.4KB -> still 6 blocks/CU. Prep untouched (isolate the change).

static constexpr int D = 64;
static constexpr int Q = 16;          // float4 quads per row
static constexpr int NPB = 64;        // nodes per bucket
static constexpr int NPB_SHIFT = 6;
static constexpr int CSHIFT = 12;     // coarse radix: 4096 nodes/bin
static constexpr int SCHUNK = 8192;   // edges per scatter block (16/thread @512)
static constexpr int CH = 4096;       // edges per gather sort chunk
static constexpr int MAXT = 32;       // max src tiles (nbins <= 2048)

// ---- index dtype sniffer: int64 nonneg <2^31 has all-zero odd dwords ----
__global__ void detect_idx_dtype(const int* __restrict__ w, int* __restrict__ flag) {
    int tid = threadIdx.x;  // one wave
    int v = w[2 * tid + 1];
    unsigned long long m = __ballot(v != 0);
    if (tid == 0) *flag = (m == 0ULL) ? 1 : 0;
}

__device__ __forceinline__ int load_idx_nt(const void* idx, long long i, int is64) {
    return is64 ? (int)__builtin_nontemporal_load(((const long long*)idx) + i)
                : __builtin_nontemporal_load(((const int*)idx) + i);
}

// ---- phase 1: fine bucket histogram, LDS-aggregated ----
__global__ __launch_bounds__(256) void bucket_hist_kernel(
        const void* __restrict__ up, const void* __restrict__ down,
        int* __restrict__ bcounts, const int* __restrict__ flag, int E, int NB) {
    extern __shared__ int lcnt[];
    const int is64 = *flag;
    for (int i = threadIdx.x; i < NB; i += blockDim.x) lcnt[i] = 0;
    __syncthreads();
    const long long total = 2LL * E;
    const long long stride = (long long)gridDim.x * blockDim.x;
    for (long long e = (long long)blockIdx.x * blockDim.x + threadIdx.x;
         e < total; e += stride) {
        const void* idx = up; long long ee = e;
        if (ee >= E) { idx = down; ee -= E; }
        int dst = load_idx_nt(idx, E + ee, is64);
        atomicAdd(&lcnt[dst >> NPB_SHIFT], 1);
    }
    __syncthreads();
    for (int i = threadIdx.x; i < NB; i += blockDim.x)
        if (lcnt[i]) atomicAdd(&bcounts[i], lcnt[i]);
}

// ---- phase 2: exclusive scan over NB buckets + coarse cursor init, one block ----
__global__ __launch_bounds__(1024) void scan_kernel(
        const int* __restrict__ counts, int* __restrict__ offsets,
        int* __restrict__ cursors, int* __restrict__ ccursor, int NB, int NCC) {
    __shared__ int sums[1024];
    const int tid = threadIdx.x;
    const int chunk = (NB + 1023) / 1024;
    const int start = tid * chunk;
    const int end = min(start + chunk, NB);
    int s = 0;
    for (int i = start; i < end; i++) s += counts[i];
    sums[tid] = s;
    __syncthreads();
    for (int off = 1; off < 1024; off <<= 1) {
        int t = (tid >= off) ? sums[tid - off] : 0;
        __syncthreads();
        sums[tid] += t;
        __syncthreads();
    }
    int run = (tid == 0) ? 0 : sums[tid - 1];
    for (int i = start; i < end; i++) {
        offsets[i] = run;
        cursors[i] = run;
        run += counts[i];
    }
    if (tid == 1023) offsets[NB] = run;
    __syncthreads();
    // coarse cursors: ccursor[c] = offsets[64c] (coarse bin = 64 fine buckets)
    for (int c = tid; c < NCC; c += 1024) ccursor[c] = offsets[min(c << 6, NB)];
}

// ---- phase 3a: generic radix scatter (register-staged, LDS-aggregated) ----
__global__ __launch_bounds__(512) void radix_scatter_kernel(
        const void* __restrict__ up, const void* __restrict__ down,
        int* __restrict__ gcursor, unsigned* __restrict__ outbuf,
        const int* __restrict__ flag, int E, int ks, int nbins) {
    extern __shared__ int lds[];
    int* cnt = lds;           // [nbins]
    int* base = lds + nbins;  // [nbins]
    const int is64 = *flag;
    const long long total = 2LL * E;
    const long long cs = (long long)blockIdx.x * SCHUNK;
    if (cs >= total) return;
    const int m = (int)(min(total, cs + (long long)SCHUNK) - cs);
    const int tid = threadIdx.x;
    const unsigned lomask = (1u << ks) - 1u;

    for (int i = tid; i < nbins; i += 512) cnt[i] = 0;
    __syncthreads();

    unsigned pr[16];
    int bkt[16];
    #pragma unroll
    for (int k = 0; k < 16; k++) {
        const int i = tid + (k << 9);
        bkt[k] = -1;
        if (i < m) {
            long long e = cs + i;
            const void* idx = up; long long ee = e;
            if (ee >= E) { idx = down; ee -= E; }
            const int src = load_idx_nt(idx, ee, is64);
            const int dst = load_idx_nt(idx, E + ee, is64);
            pr[k] = ((unsigned)src << ks) | ((unsigned)dst & lomask);
            bkt[k] = dst >> ks;
            atomicAdd(&cnt[bkt[k]], 1);
        }
    }
    __syncthreads();
    for (int i = tid; i < nbins; i += 512) {
        int c = cnt[i];
        base[i] = c ? atomicAdd(&gcursor[i], c) : 0;
        cnt[i] = 0;  // reuse as local cursor
    }
    __syncthreads();
    #pragma unroll
    for (int k = 0; k < 16; k++) {
        if (bkt[k] >= 0) {
            int pos = base[bkt[k]] + atomicAdd(&cnt[bkt[k]], 1);
            outbuf[pos] = pr[k];
        }
    }
}

// ---- phase 3b: fine scatter within coarse segments ----
__global__ __launch_bounds__(512) void fine_scatter_kernel(
        const unsigned* __restrict__ packed1, int* __restrict__ gcursor,
        unsigned* __restrict__ packed2, const int* __restrict__ offsets,
        int NB, long long total) {
    __shared__ int cnt[64], base[64];
    __shared__ int sc_lo, sc_hi;
    const long long cs = (long long)blockIdx.x * SCHUNK;
    if (cs >= total) return;
    const long long ce = min(total, cs + (long long)SCHUNK);
    const int tid = threadIdx.x;

    if (tid == 0) {
        int c = 0;
        while ((long long)offsets[min((c + 1) << 6, NB)] <= cs) c++;
        sc_lo = c;
        while ((long long)offsets[min((c + 1) << 6, NB)] < ce) c++;
        sc_hi = c;
    }
    __syncthreads();
    const int clo = sc_lo, chi = sc_hi;

    for (int c = clo; c <= chi; c++) {
        const int fb0 = c << 6;
        const long long lo = max(cs, (long long)offsets[min(fb0, NB)]);
        const long long hi = min(ce, (long long)offsets[min(fb0 + 64, NB)]);
        if (lo >= hi) continue;
        if (tid < 64) cnt[tid] = 0;
        __syncthreads();
        for (long long i = lo + tid; i < hi; i += 512) {
            unsigned p = packed1[i];
            atomicAdd(&cnt[(p >> NPB_SHIFT) & 63], 1);
        }
        __syncthreads();
        if (tid < 64) {
            int cc = cnt[tid];
            base[tid] = cc ? atomicAdd(&gcursor[fb0 + tid], cc) : 0;
            cnt[tid] = 0;
        }
        __syncthreads();
        for (long long i = lo + tid; i < hi; i += 512) {
            unsigned p = packed1[i];
            int f = (p >> NPB_SHIFT) & 63;
            int pos = base[f] + atomicAdd(&cnt[f], 1);
            packed2[pos] = ((p >> CSHIFT) << NPB_SHIFT) | (p & (NPB - 1));
        }
        __syncthreads();
    }
}

// ---- phase 4: per-bucket counting sort (tile-major key, PAIR-ALIGNED bins) +
// tile-swept gather with uint2 (b64) index reads and packed bin bounds. ----
__global__ __launch_bounds__(256) void bucket_gather_kernel(
        const float* __restrict__ x, const int* __restrict__ offsets,
        const unsigned* __restrict__ packed, float* __restrict__ out,
        int N, int shift, int NT) {
    extern __shared__ int lds[];
    const int nbins = NT * NPB;
    const int SORTN = CH + nbins + 8;
    unsigned* sorted = (unsigned*)lds;        // [SORTN], bins pair-aligned
    int* cnt = lds + SORTN;                   // [nbins]: counts -> cursor -> ends
    int* binoff = cnt + nbins;                // [nbins]: aligned starts -> packed

    const int b = blockIdx.x;
    const int tid = threadIdx.x;
    const int g = tid >> 4;   // group 0..15 (owns nodes 4g..4g+3)
    const int q = tid & 15;   // quad within row
    const int beg = offsets[b], end = offsets[b + 1];
    const float* xq = x + q * 4;

    float4 acc[4];
    acc[0] = acc[1] = acc[2] = acc[3] = make_float4(0.f, 0.f, 0.f, 0.f);

#define ROWLD(P) (*(const float4*)(xq + ((long long)((P) >> NPB_SHIFT)) * D))

    for (int cs = beg; cs < end; cs += CH) {
        const int m = min(CH, end - cs);
        for (int i = tid; i < nbins; i += 256) cnt[i] = 0;
        __syncthreads();
        // hist + register stage (CH == 16*256); key = tile*NPB + dstlo
        unsigned pr[16];
        #pragma unroll
        for (int k = 0; k < 16; k++) {
            const int i = tid + (k << 8);
            if (i < m) {
                unsigned p = __builtin_nontemporal_load(packed + cs + i);
                pr[k] = p;
                int key = (int)((p >> (NPB_SHIFT + shift)) << NPB_SHIFT) | (int)(p & (NPB - 1));
                atomicAdd(&cnt[key], 1);
            }
        }
        __syncthreads();
        if (tid < 64) {  // wave 0: scan with pad-to-even allocation
            const int K = (nbins + 63) >> 6;
            const int base = tid * K;
            int S = 0;
            for (int k = 0; k < K; k++) {
                int i = base + k;
                if (i < nbins) { int c = cnt[i]; S += c + (c & 1); }
            }
            int inc = S;
            #pragma unroll
            for (int off = 1; off < 64; off <<= 1) {
                int t = __shfl_up(inc, off, 64);
                if (tid >= off) inc += t;
            }
            int run = inc - S;  // exclusive lane offset (even)
            for (int k = 0; k < K; k++) {
                int i = base + k;
                if (i < nbins) {
                    int c = cnt[i];
                    binoff[i] = run;   // aligned start
                    cnt[i] = run;      // cursor
                    run += c + (c & 1);
                }
            }
        }
        __syncthreads();
        #pragma unroll
        for (int k = 0; k < 16; k++) {
            const int i = tid + (k << 8);
            if (i < m) {
                unsigned p = pr[k];
                int key = (int)((p >> (NPB_SHIFT + shift)) << NPB_SHIFT) | (int)(p & (NPB - 1));
                int pos = atomicAdd(&cnt[key], 1);
                sorted[pos] = p;
            }
        }
        __syncthreads();
        // pack bounds: binoff = start | end<<16 (both < 2^14)
        for (int i = tid; i < nbins; i += 256) binoff[i] |= cnt[i] << 16;
        __syncthreads();
        // tile-swept accumulation: uint2 (b64) index reads, 8-deep main loop
        for (int t = 0; t < NT; t++) {
            #pragma unroll
            for (int j = 0; j < 4; j++) {
                const int key = t * NPB + 4 * g + j;
                const unsigned se = (unsigned)binoff[key];
                int e = (int)(se & 0xFFFFu);
                const int re = (int)(se >> 16);
                for (; e + 8 <= re; e += 8) {
                    const uint2 p01 = *(const uint2*)(sorted + e);
                    const uint2 p23 = *(const uint2*)(sorted + e + 2);
                    const uint2 p45 = *(const uint2*)(sorted + e + 4);
                    const uint2 p67 = *(const uint2*)(sorted + e + 6);
                    const float4 v0 = ROWLD(p01.x), v1 = ROWLD(p01.y);
                    const float4 v2 = ROWLD(p23.x), v3 = ROWLD(p23.y);
                    const float4 v4 = ROWLD(p45.x), v5 = ROWLD(p45.y);
                    const float4 v6 = ROWLD(p67.x), v7 = ROWLD(p67.y);
                    acc[j].x += ((v0.x + v1.x) + (v2.x + v3.x)) + ((v4.x + v5.x) + (v6.x + v7.x));
                    acc[j].y += ((v0.y + v1.y) + (v2.y + v3.y)) + ((v4.y + v5.y) + (v6.y + v7.y));
                    acc[j].z += ((v0.z + v1.z) + (v2.z + v3.z)) + ((v4.z + v5.z) + (v6.z + v7.z));
                    acc[j].w += ((v0.w + v1.w) + (v2.w + v3.w)) + ((v4.w + v5.w) + (v6.w + v7.w));
                }
                for (; e < re; e += 2) {
                    const uint2 pp = *(const uint2*)(sorted + e);
                    const float4 v0 = ROWLD(pp.x);
                    acc[j].x += v0.x; acc[j].y += v0.y; acc[j].z += v0.z; acc[j].w += v0.w;
                    if (e + 1 < re) {   // group-uniform branch; gap slot never used
                        const float4 v1 = ROWLD(pp.y);
                        acc[j].x += v1.x; acc[j].y += v1.y; acc[j].z += v1.z; acc[j].w += v1.w;
                    }
                }
            }
        }
        __syncthreads();  // gather reads done before next chunk reuses LDS
    }
#undef ROWLD

    const int node0 = b * NPB;
    #pragma unroll
    for (int j = 0; j < 4; j++) {
        const int node = node0 + 4 * g + j;
        if (node < N)
            *(float4*)(out + (long long)node * D + q * 4) = acc[j];
    }
}

// ---- fallback: direct fp32 atomics (R1), needs no workspace ----
__global__ __launch_bounds__(256) void scatter_add_kernel(
        const float* __restrict__ x, const void* __restrict__ up_idx,
        const void* __restrict__ down_idx, float* __restrict__ out,
        const int* __restrict__ dtype_flag, int num_edges) {
    const int is64 = *dtype_flag;
    const long long total = 2LL * num_edges * Q;
    const long long stride = (long long)gridDim.x * blockDim.x;
    for (long long t = (long long)blockIdx.x * blockDim.x + threadIdx.x;
         t < total; t += stride) {
        const int quad = (int)(t & (Q - 1));
        long long eg = t >> 4;
        const void* idx = up_idx;
        if (eg >= num_edges) { idx = down_idx; eg -= num_edges; }
        int src = load_idx_nt(idx, eg, is64);
        int dst = load_idx_nt(idx, num_edges + eg, is64);
        const float4 v = *(const float4*)(x + (long long)src * D + quad * 4);
        float* o = out + (long long)dst * D + quad * 4;
        unsafeAtomicAdd(o + 0, v.x);
        unsafeAtomicAdd(o + 1, v.y);
        unsafeAtomicAdd(o + 2, v.z);
        unsafeAtomicAdd(o + 3, v.w);
    }
}

extern "C" void kernel_launch(void* const* d_in, const int* in_sizes, int n_in,
                              void* d_out, int out_size, void* d_ws, size_t ws_size,
                              hipStream_t stream) {
    const float* x = (const float*)d_in[0];
    const void* up_idx = d_in[1];
    const void* down_idx = d_in[2];
    float* out = (float*)d_out;

    const int E = in_sizes[1] / 2;   // [2, E]
    const int N = out_size / D;      // [N, 64]
    const int NB = (N + NPB - 1) / NPB;
    const int NCC = (NB + 63) >> 6;  // coarse bins (4096 nodes each)
    const long long Etot = 2LL * E;

    // src tile shift: 8192 rows (2MB) preferred; coarsen so NT <= MAXT
    int shift = 13;
    while ((((long long)(N - 1) >> shift) + 1) > MAXT) shift++;
    const int NT = (int)(((long long)(N - 1) >> shift) + 1);

    // ws layout (ints):
    // flag(64) | counts[NB] | offsets[NB+16] | cursors[NB] | ccursor[NCCpad] | packed1[Etot] | packed2[Etot]
    int* ws_i = (int*)d_ws;
    int* flag = ws_i;
    int* counts = ws_i + 64;
    int* offsets = counts + NB;
    int* cursors = offsets + NB + 16;
    int* ccursor = cursors + NB;
    const int nccpad = (NCC + 15) & ~15;
    unsigned* packed1 = (unsigned*)(ccursor + nccpad);
    unsigned* packed2 = packed1 + Etot;

    const size_t need1 = ((size_t)64 + 3LL * NB + 16 + nccpad + Etot) * 4 + 64;
    const size_t need2 = ((size_t)64 + 3LL * NB + 16 + nccpad + 2LL * Etot) * 4 + 64;
    const bool twopass = (ws_size >= need2) && (N <= (1 << 20)) && Etot < (1LL << 31);
    const bool onepass = !twopass && (ws_size >= need1) && (N <= (1 << 25)) && Etot < (1LL << 31);

    detect_idx_dtype<<<1, 64, 0, stream>>>((const int*)up_idx, flag);

    if (twopass || onepass) {
        hipMemsetAsync(counts, 0, (size_t)NB * sizeof(int), stream);
        bucket_hist_kernel<<<2048, 256, NB * sizeof(int), stream>>>(
            up_idx, down_idx, counts, flag, E, NB);
        scan_kernel<<<1, 1024, 0, stream>>>(counts, offsets, cursors, ccursor, NB, NCC);
        const int sblocks = (int)((Etot + SCHUNK - 1) / SCHUNK);
        const unsigned* gsrc;
        if (twopass) {
            radix_scatter_kernel<<<sblocks, 512, 2 * NCC * sizeof(int), stream>>>(
                up_idx, down_idx, ccursor, packed1, flag, E, CSHIFT, NCC);
            fine_scatter_kernel<<<sblocks, 512, 0, stream>>>(
                packed1, cursors, packed2, offsets, NB, Etot);
            gsrc = packed2;
        } else {
            radix_scatter_kernel<<<sblocks, 512, 2 * NB * sizeof(int), stream>>>(
                up_idx, down_idx, cursors, packed1, flag, E, NPB_SHIFT, NB);
            gsrc = packed1;
        }
        const int nbins = NT * NPB;
        const int sortn = CH + nbins + 8;
        const size_t glds = (size_t)(sortn + 2 * nbins) * 4;
        bucket_gather_kernel<<<NB, 256, glds, stream>>>(
            x, offsets, gsrc, out, N, shift, NT);
    } else {
        hipMemsetAsync(d_out, 0, (size_t)out_size * sizeof(float), stream);
        scatter_add_kernel<<<8192, 256, 0, stream>>>(x, up_idx, down_idx, out, flag, E);
    }
}